// Round 1
// baseline (92.855 us; speedup 1.0000x reference)
//
#include <hip/hip_runtime.h>

// Problem constants (match reference)
#define BB 32
#define LC 2048
#define PP 512
#define DC 128
#define DP 768
#define DOUT (DC + DP)          // 896 floats per output row
#define ROWS 4                  // char rows per block (= SPAN in the well-formed input)
#define F4_ROW (DOUT / 4)       // 224 float4 per output row
#define F4_CHAR (DC / 4)        // 32 float4 char part
#define F4_SUB (DP / 4)         // 192 float4 subword part

__global__ __launch_bounds__(256, 4)
void emb_concat_kernel(const int* __restrict__ seq,      // [B, LC] int32
                       const int* __restrict__ offs,     // [B, P, 2] int32
                       const float4* __restrict__ pretr, // [B, P, DP/4]
                       const float4* __restrict__ cemb,  // [V, DC/4]
                       float4* __restrict__ out)         // [B, LC, DOUT/4]
{
    const int blk = blockIdx.x;                 // 0 .. B*LC/ROWS - 1
    const int b   = blk / (LC / ROWS);
    const int g   = blk % (LC / ROWS);
    const int k0  = g * ROWS;
    const int t   = threadIdx.x;

    __shared__ int sh_c[ROWS];      // char ids
    __shared__ int sh_p[ROWS];      // subword index
    __shared__ int sh_v[ROWS];      // valid flag

    if (t < ROWS) {
        const int k = k0 + t;
        sh_c[t] = seq[b * LC + k];
        const int* ob = offs + b * PP * 2;      // interleaved [start,end] pairs
        // upper_bound on starts: first idx with start > k
        int lo = 0, hi = PP;
        while (lo < hi) {
            int mid = (lo + hi) >> 1;
            if (ob[2 * mid] <= k) lo = mid + 1; else hi = mid;
        }
        int idx = lo - 1;
        if (idx < 0) idx = 0;                   // clip like the reference
        const int s = ob[2 * idx];
        const int e = ob[2 * idx + 1];
        sh_p[t] = idx;
        sh_v[t] = (k >= s && k < e) ? 1 : 0;
    }
    __syncthreads();

    const float4 zero4 = make_float4(0.f, 0.f, 0.f, 0.f);
    float4* orow = out + (size_t)(b * LC + k0) * F4_ROW;   // contiguous 4-row region

    #pragma unroll
    for (int i = t; i < ROWS * F4_ROW; i += 256) {
        const int r  = i / F4_ROW;
        const int d4 = i - r * F4_ROW;
        float4 v;
        if (d4 < F4_CHAR) {
            v = cemb[(size_t)sh_c[r] * F4_CHAR + d4];
        } else {
            v = sh_v[r] ? pretr[(size_t)(b * PP + sh_p[r]) * F4_SUB + (d4 - F4_CHAR)]
                        : zero4;
        }
        orow[i] = v;
    }
}

extern "C" void kernel_launch(void* const* d_in, const int* in_sizes, int n_in,
                              void* d_out, int out_size, void* d_ws, size_t ws_size,
                              hipStream_t stream) {
    const int*    seq   = (const int*)d_in[0];
    const int*    offs  = (const int*)d_in[1];
    const float4* pretr = (const float4*)d_in[2];
    const float4* cemb  = (const float4*)d_in[3];
    float4*       out   = (float4*)d_out;

    const int nblocks = BB * (LC / ROWS);   // 16384
    emb_concat_kernel<<<nblocks, 256, 0, stream>>>(seq, offs, pretr, cemb, out);
}

// Round 2
// 85.270 us; speedup vs baseline: 1.0890x; 1.0890x over previous
//
#include <hip/hip_runtime.h>

// Problem constants (match reference)
#define BB 32
#define LC 2048
#define PP 512
#define DC 128
#define DP 768
#define DOUT (DC + DP)          // 896 floats per output row
#define F4_ROW (DOUT / 4)       // 224 float4 per output row
#define F4_CHAR (DC / 4)        // 32 float4 char part
#define F4_SUB (DP / 4)         // 192 float4 subword part
#define ROWS 8                  // char rows per block in K2: 8*224 = 1792 = 7*256 exact

// ---------------- K1: per-char-position subword map ----------------
// map[b*LC + k] = subword index p if k in [start_p, end_p), else -1
__global__ __launch_bounds__(256)
void build_map_kernel(const int* __restrict__ offs,  // [B, P, 2]
                      int* __restrict__ map)         // [B*LC]
{
    const int gid = blockIdx.x * 256 + threadIdx.x;  // 0 .. B*LC-1
    const int b = gid >> 11;                         // / LC
    const int k = gid & (LC - 1);
    const int* ob = offs + b * PP * 2;
    // upper_bound on starts: first idx with start > k
    int lo = 0, hi = PP;
    #pragma unroll
    for (int it = 0; it < 9; ++it) {                 // ceil(log2(512)) = 9
        int mid = (lo + hi) >> 1;
        if (lo < hi) {
            if (ob[2 * mid] <= k) lo = mid + 1; else hi = mid;
        }
    }
    int idx = lo - 1;
    if (idx < 0) idx = 0;                            // clip like the reference
    const int s = ob[2 * idx];
    const int e = ob[2 * idx + 1];
    map[gid] = (k >= s && k < e) ? idx : -1;
}

// ---------------- K2: pure streaming concat ----------------
__global__ __launch_bounds__(256)
void stream_kernel(const int* __restrict__ seq,      // [B, LC]
                   const int* __restrict__ map,      // [B*LC]
                   const float4* __restrict__ pretr, // [B, P, DP/4]
                   const float4* __restrict__ cemb,  // [V, DC/4]
                   float4* __restrict__ out)         // [B, LC, DOUT/4]
{
    const int blk = blockIdx.x;                      // 0 .. B*LC/ROWS - 1
    const int b   = blk / (LC / ROWS);
    const int k0  = blk * ROWS;                      // global row base (b*LC + k)
    const int t   = threadIdx.x;

    const float4 zero4 = make_float4(0.f, 0.f, 0.f, 0.f);
    float4* oreg = out + (size_t)k0 * F4_ROW;        // contiguous ROWS-row region

    #pragma unroll
    for (int j = 0; j < (ROWS * F4_ROW) / 256; ++j) {
        const int i  = t + j * 256;
        const int r  = i / F4_ROW;                   // const-div -> magic mul
        const int d4 = i - r * F4_ROW;
        const int bk = k0 + r;
        float4 v;
        if (d4 < F4_CHAR) {
            v = cemb[(size_t)seq[bk] * F4_CHAR + d4];
        } else {
            const int p = map[bk];
            v = (p >= 0) ? pretr[((size_t)b * PP + p) * F4_SUB + (d4 - F4_CHAR)]
                         : zero4;
        }
        oreg[i] = v;
    }
}

// ---------------- fallback (search fused, no workspace) ----------------
__global__ __launch_bounds__(256)
void fused_kernel(const int* __restrict__ seq,
                  const int* __restrict__ offs,
                  const float4* __restrict__ pretr,
                  const float4* __restrict__ cemb,
                  float4* __restrict__ out)
{
    const int blk = blockIdx.x;
    const int b   = blk / (LC / ROWS);
    const int k0  = blk * ROWS;
    const int t   = threadIdx.x;
    const int* ob = offs + b * PP * 2;

    const float4 zero4 = make_float4(0.f, 0.f, 0.f, 0.f);
    float4* oreg = out + (size_t)k0 * F4_ROW;

    #pragma unroll
    for (int j = 0; j < (ROWS * F4_ROW) / 256; ++j) {
        const int i  = t + j * 256;
        const int r  = i / F4_ROW;
        const int d4 = i - r * F4_ROW;
        const int bk = k0 + r;
        const int k  = bk - b * LC;
        float4 v;
        if (d4 < F4_CHAR) {
            v = cemb[(size_t)seq[bk] * F4_CHAR + d4];
        } else {
            int lo = 0, hi = PP;
            while (lo < hi) {
                int mid = (lo + hi) >> 1;
                if (ob[2 * mid] <= k) lo = mid + 1; else hi = mid;
            }
            int idx = lo - 1;
            if (idx < 0) idx = 0;
            const int s = ob[2 * idx];
            const int e = ob[2 * idx + 1];
            v = (k >= s && k < e)
                    ? pretr[((size_t)b * PP + idx) * F4_SUB + (d4 - F4_CHAR)]
                    : zero4;
        }
        oreg[i] = v;
    }
}

extern "C" void kernel_launch(void* const* d_in, const int* in_sizes, int n_in,
                              void* d_out, int out_size, void* d_ws, size_t ws_size,
                              hipStream_t stream) {
    const int*    seq   = (const int*)d_in[0];
    const int*    offs  = (const int*)d_in[1];
    const float4* pretr = (const float4*)d_in[2];
    const float4* cemb  = (const float4*)d_in[3];
    float4*       out   = (float4*)d_out;

    const int nrows   = BB * LC;                 // 65536
    const int nblocks = nrows / ROWS;            // 8192

    if (ws_size >= (size_t)nrows * sizeof(int)) {
        int* map = (int*)d_ws;
        build_map_kernel<<<nrows / 256, 256, 0, stream>>>(offs, map);
        stream_kernel<<<nblocks, 256, 0, stream>>>(seq, map, pretr, cemb, out);
    } else {
        fused_kernel<<<nblocks, 256, 0, stream>>>(seq, offs, pretr, cemb, out);
    }
}

// Round 4
// 52.895 us; speedup vs baseline: 1.7554x; 1.6120x over previous
//
#include <hip/hip_runtime.h>

// Problem constants (match reference)
#define BB 32
#define LC 2048
#define PP 512
#define DC 128
#define DP 768
#define DOUT (DC + DP)          // 896 floats per output row
#define F4_ROW (DOUT / 4)       // 224 float4 per output row
#define F4_CHAR (DC / 4)        // 32 float4 char part
#define F4_SUB (DP / 4)         // 192 float4 subword part
#define ROWS 8                  // rows per block: char part = 8*32 = 256 f4 = 1 iter

typedef float f4 __attribute__((ext_vector_type(4)));   // builtin-compatible 16B vector

// Fused: search overlapped with char phase, then pure streaming pretr phase.
__global__ __launch_bounds__(256)
void emb_fused_kernel(const int* __restrict__ seq,   // [B, LC]
                      const int* __restrict__ offs,  // [B, P, 2]
                      const f4* __restrict__ pretr,  // [B, P, DP/4]
                      const f4* __restrict__ cemb,   // [V, DC/4]
                      f4* __restrict__ out)          // [B, LC, DOUT/4]
{
    const int blk = blockIdx.x;                  // 0 .. B*LC/ROWS - 1
    const int b   = blk / (LC / ROWS);
    const int k0  = blk * ROWS;                  // global row base (b*LC + k)
    const int kk0 = k0 - b * LC;                 // local char position base
    const int t   = threadIdx.x;

    __shared__ int sh_p[ROWS];                   // subword index, or -1 if uncovered

    // ---- Phase A: char part (one full iteration, independent of the search) ----
    // thread t -> row r = t>>5, d4 = t&31
    {
        const int r  = t >> 5;
        const int d4 = t & 31;
        const int s  = seq[k0 + r];
        const f4 v = cemb[(size_t)s * F4_CHAR + d4];
        __builtin_nontemporal_store(v, out + (size_t)(k0 + r) * F4_ROW + d4);
    }

    // ---- Search (lanes 0..7 of wave 0; 8 independent chains = 1 chain latency) ----
    if (t < ROWS) {
        const int k   = kk0 + t;
        const int* ob = offs + b * PP * 2;       // interleaved [start,end]
        int lo = 0, hi = PP;
        while (lo < hi) {
            int mid = (lo + hi) >> 1;
            if (ob[2 * mid] <= k) lo = mid + 1; else hi = mid;
        }
        int idx = lo - 1;
        if (idx < 0) idx = 0;                    // clip like the reference
        const int s = ob[2 * idx];
        const int e = ob[2 * idx + 1];
        sh_p[t] = (k >= s && k < e) ? idx : -1;
    }
    __syncthreads();

    // ---- Phase B: pretr part, pure streaming (6 exact iterations) ----
    const f4 zero4 = (f4){0.f, 0.f, 0.f, 0.f};
    f4* oreg = out + (size_t)k0 * F4_ROW;
    const size_t pbase = (size_t)b * PP;

    #pragma unroll
    for (int j = 0; j < (ROWS * F4_SUB) / 256; ++j) {
        const int idx = t + j * 256;             // 0 .. 1535
        const int r   = idx / F4_SUB;            // 192 per row -> magic mul
        const int dd  = idx - r * F4_SUB;        // 0 .. 191
        const int p   = sh_p[r];
        const f4 v = (p >= 0) ? pretr[(pbase + p) * F4_SUB + dd] : zero4;
        __builtin_nontemporal_store(v, oreg + r * F4_ROW + F4_CHAR + dd);
    }
}

extern "C" void kernel_launch(void* const* d_in, const int* in_sizes, int n_in,
                              void* d_out, int out_size, void* d_ws, size_t ws_size,
                              hipStream_t stream) {
    const int* seq   = (const int*)d_in[0];
    const int* offs  = (const int*)d_in[1];
    const f4*  pretr = (const f4*)d_in[2];
    const f4*  cemb  = (const f4*)d_in[3];
    f4*        out   = (f4*)d_out;

    const int nblocks = BB * LC / ROWS;          // 8192
    emb_fused_kernel<<<nblocks, 256, 0, stream>>>(seq, offs, pretr, cemb, out);
}

// Round 5
// 52.600 us; speedup vs baseline: 1.7653x; 1.0056x over previous
//
#include <hip/hip_runtime.h>

// Problem constants (match reference)
#define BB 32
#define LC 2048
#define PP 512
#define DC 128
#define DP 768
#define DOUT (DC + DP)          // 896 floats per output row
#define F4_ROW (DOUT / 4)       // 224 float4 per output row
#define F4_CHAR (DC / 4)        // 32 float4 char part
#define F4_SUB (DP / 4)         // 192 float4 subword part
#define ROWS 16                 // rows per block: char part = 16*32 = 512 f4 = 1 iter
#define NT 512                  // threads per block

typedef float f4 __attribute__((ext_vector_type(4)));   // builtin-compatible 16B vector

// Fused: search overlapped with char phase, then pure streaming pretr phase.
__global__ __launch_bounds__(NT)
void emb_fused_kernel(const int* __restrict__ seq,   // [B, LC]
                      const int* __restrict__ offs,  // [B, P, 2]
                      const f4* __restrict__ pretr,  // [B, P, DP/4]
                      const f4* __restrict__ cemb,   // [V, DC/4]
                      f4* __restrict__ out)          // [B, LC, DOUT/4]
{
    const int blk = blockIdx.x;                  // 0 .. B*LC/ROWS - 1
    const int b   = blk / (LC / ROWS);
    const int k0  = blk * ROWS;                  // global row base (b*LC + k)
    const int kk0 = k0 - b * LC;                 // local char position base
    const int t   = threadIdx.x;

    __shared__ int sh_p[ROWS];                   // subword index, or -1 if uncovered

    // ---- Phase A: char part (one full iteration, independent of the search) ----
    // thread t -> row r = t>>5, d4 = t&31   (16 rows x 32 f4 = 512 threads exactly)
    {
        const int r  = t >> 5;
        const int d4 = t & 31;
        const int s  = seq[k0 + r];
        const f4 v = cemb[(size_t)s * F4_CHAR + d4];
        __builtin_nontemporal_store(v, out + (size_t)(k0 + r) * F4_ROW + d4);
    }

    // ---- Search (lanes 0..15 of wave 0; 16 independent chains = 1 chain latency) ----
    if (t < ROWS) {
        const int k   = kk0 + t;
        const int* ob = offs + b * PP * 2;       // interleaved [start,end]
        int lo = 0, hi = PP;
        while (lo < hi) {
            int mid = (lo + hi) >> 1;
            if (ob[2 * mid] <= k) lo = mid + 1; else hi = mid;
        }
        int idx = lo - 1;
        if (idx < 0) idx = 0;                    // clip like the reference
        const int s = ob[2 * idx];
        const int e = ob[2 * idx + 1];
        sh_p[t] = (k >= s && k < e) ? idx : -1;
    }
    __syncthreads();

    // ---- Phase B: pretr part, pure streaming (6 exact iterations) ----
    const f4 zero4 = (f4){0.f, 0.f, 0.f, 0.f};
    f4* oreg = out + (size_t)k0 * F4_ROW;
    const size_t pbase = (size_t)b * PP;

    #pragma unroll
    for (int j = 0; j < (ROWS * F4_SUB) / NT; ++j) {
        const int idx = t + j * NT;              // 0 .. 3071
        const int r   = idx / F4_SUB;            // 192 per row -> magic mul
        const int dd  = idx - r * F4_SUB;        // 0 .. 191
        const int p   = sh_p[r];
        const f4 v = (p >= 0) ? pretr[(pbase + p) * F4_SUB + dd] : zero4;
        __builtin_nontemporal_store(v, oreg + r * F4_ROW + F4_CHAR + dd);
    }
}

extern "C" void kernel_launch(void* const* d_in, const int* in_sizes, int n_in,
                              void* d_out, int out_size, void* d_ws, size_t ws_size,
                              hipStream_t stream) {
    const int* seq   = (const int*)d_in[0];
    const int* offs  = (const int*)d_in[1];
    const f4*  pretr = (const f4*)d_in[2];
    const f4*  cemb  = (const f4*)d_in[3];
    f4*        out   = (f4*)d_out;

    const int nblocks = BB * LC / ROWS;          // 4096
    emb_fused_kernel<<<nblocks, NT, 0, stream>>>(seq, offs, pretr, cemb, out);
}